// Round 3
// baseline (1670.439 us; speedup 1.0000x reference)
//
#include <hip/hip_runtime.h>

#define N_NODES 20000
#define N_EDGES 320000
#define CH 68

__device__ __forceinline__ float sigm(float x) { return 1.0f / (1.0f + __expf(-x)); }
// jax.nn.gelu approximate=True == x*sigmoid(1.5957691*(x+0.044715x^3))
__device__ __forceinline__ float gelu(float x) {
    return x * sigm(1.5957691216057308f * (x + 0.044715f * x * x * x));
}

__global__ void init_kernel(const float* __restrict__ s0, const float* __restrict__ p0,
                            float* __restrict__ s, float4* __restrict__ v4,
                            float* __restrict__ cnt) {
    int idx = blockIdx.x * 256 + threadIdx.x;
    if (idx < N_NODES * 16) s[idx] = s0[idx];
    if (idx < N_NODES) {
        v4[idx] = make_float4(p0[idx * 3], p0[idx * 3 + 1], p0[idx * 3 + 2], 0.f);
        cnt[idx] = 0.f;
    }
}

__global__ void count_kernel(const int* __restrict__ rcv, float* __restrict__ cnt) {
    int e = blockIdx.x * 256 + threadIdx.x;
    if (e < N_EDGES) unsafeAtomicAdd(&cnt[rcv[e]], 1.0f);
}

__global__ __launch_bounds__(64, 4) void edge_kernel(
    const float4* __restrict__ s4, const float4* __restrict__ v4,
    const int* __restrict__ snd, const int* __restrict__ rcv,
    const float* __restrict__ Ws0, const float* __restrict__ bs0, const float* __restrict__ Wv0,
    const float* __restrict__ Ws1, const float* __restrict__ bs1, const float* __restrict__ Wv1,
    float* __restrict__ agg) {
    __shared__ float lmain[64 * 33];  // stride 33: coprime with 32 -> conflict-free
    __shared__ float lav[64 * 5];     // stride 5: coprime with 32
    const int lane = threadIdx.x;
    const int e = blockIdx.x * 64 + lane;  // grid = 5000 covers N_EDGES exactly
    const int i = snd[e], j = rcv[e];

    const float4 vi4 = v4[i], vj4 = v4[j];
    const float vi0 = vi4.x, vi1 = vi4.y, vi2 = vi4.z;
    const float vj0 = vj4.x, vj1 = vj4.y, vj2 = vj4.z;
    const float r0 = vi0 - vj0, r1 = vi1 - vj1, r2 = vi2 - vj2;
    const float nrm = sqrtf(r0 * r0 + r1 * r1 + r2 * r2);
    const float scl = 1.7320508075688772f / (nrm + 1e-8f);  // sqrt(3) * rhat
    const float a0 = r0 * scl, a1 = r1 * scl, a2 = r2 * scl;

    float xs[32];
    {
        float4 A = s4[i * 4 + 0], B = s4[i * 4 + 1], C = s4[i * 4 + 2], D = s4[i * 4 + 3];
        xs[0] = A.x; xs[1] = A.y; xs[2] = A.z; xs[3] = A.w;
        xs[4] = B.x; xs[5] = B.y; xs[6] = B.z; xs[7] = B.w;
        xs[8] = C.x; xs[9] = C.y; xs[10] = C.z; xs[11] = C.w;
        xs[12] = D.x; xs[13] = D.y; xs[14] = D.z; xs[15] = D.w;
        A = s4[j * 4 + 0]; B = s4[j * 4 + 1]; C = s4[j * 4 + 2]; D = s4[j * 4 + 3];
        xs[16] = A.x; xs[17] = A.y; xs[18] = A.z; xs[19] = A.w;
        xs[20] = B.x; xs[21] = B.y; xs[22] = B.z; xs[23] = B.w;
        xs[24] = C.x; xs[25] = C.y; xs[26] = C.z; xs[27] = C.w;
        xs[28] = D.x; xs[29] = D.y; xs[30] = D.z; xs[31] = D.w;
    }
    const float di = vi0 * a0 + vi1 * a1 + vi2 * a2;
    const float dj = vj0 * a0 + vj1 * a1 + vj2 * a2;

    // ---- TPLG 0 ----
    float sl[32];
#pragma unroll
    for (int o = 0; o < 32; o++) sl[o] = bs0[o] + di * Ws0[32 * 32 + o] + dj * Ws0[33 * 32 + o];
    float al[16];
#pragma unroll
    for (int q = 0; q < 16; q++) al[q] = 0.f;
#pragma unroll
    for (int p = 0; p < 32; p++) {
        const float x = xs[p];
#pragma unroll
        for (int o = 0; o < 32; o++) sl[o] += x * Ws0[p * 32 + o];
#pragma unroll
        for (int q = 0; q < 16; q++) al[q] += x * Wv0[p * 16 + q];
    }
    float ms[16], mv0[16], mv1[16], mv2[16];
#pragma unroll
    for (int q = 0; q < 16; q++) {
        const float g = sigm(sl[q]);
        const float w32 = Wv0[32 * 16 + q], w33 = Wv0[33 * 16 + q];
        mv0[q] = (al[q] * a0 + w32 * vi0 + w33 * vj0) * g;
        mv1[q] = (al[q] * a1 + w32 * vi1 + w33 * vj1) * g;
        mv2[q] = (al[q] * a2 + w32 * vi2 + w33 * vj2) * g;
    }
#pragma unroll
    for (int p = 0; p < 16; p++) ms[p] = gelu(sl[16 + p]);

    // ---- TPLG 1 ----
    float sl2[32];
#pragma unroll
    for (int o = 0; o < 32; o++) sl2[o] = bs1[o];
#pragma unroll
    for (int p = 0; p < 16; p++) {
        const float x = ms[p];
#pragma unroll
        for (int o = 0; o < 32; o++) sl2[o] += x * Ws1[p * 32 + o];
    }
#pragma unroll
    for (int q = 0; q < 16; q++) {
        const float x = mv0[q] * a0 + mv1[q] * a1 + mv2[q] * a2;
#pragma unroll
        for (int o = 0; o < 32; o++) sl2[o] += x * Ws1[(16 + q) * 32 + o];
    }
    // final messages: scalars fs[16] = gelu, vectors u[16][3] gated
    float fs[16];
#pragma unroll
    for (int p = 0; p < 16; p++) fs[p] = gelu(sl2[16 + p]);
    float u0[16], u1[16], u2[16];
#pragma unroll
    for (int q = 0; q < 16; q++) {
        const float g = sigm(sl2[q]);
        float be = 0.f;
#pragma unroll
        for (int p = 0; p < 16; p++) be += ms[p] * Wv1[p * 16 + q];
        float x0 = be * a0, x1 = be * a1, x2 = be * a2;
#pragma unroll
        for (int p = 0; p < 16; p++) {
            const float w = Wv1[(16 + p) * 16 + q];
            x0 += mv0[p] * w; x1 += mv1[p] * w; x2 += mv2[p] * w;
        }
        u0[q] = x0 * g; u1[q] = x1 * g; u2[q] = x2 * g;
    }

    float* row = lmain + lane * 33;
    // ---- PASS A: channels 0..31 (ms[0..15], mv channels 16..31) ----
#pragma unroll
    for (int c = 0; c < 16; c++) row[c] = fs[c];
#pragma unroll
    for (int c = 16; c < 32; c++) {
        const int qq = (c - 16) / 3, r = (c - 16) - qq * 3;
        row[c] = (r == 0) ? u0[qq] : (r == 1) ? u1[qq] : u2[qq];
    }
    lav[lane * 5 + 0] = a0; lav[lane * 5 + 1] = a1; lav[lane * 5 + 2] = a2;
    __syncthreads();
    const int half = lane >> 5;
    const int col = lane & 31;
#pragma unroll 4
    for (int it = 0; it < 32; it++) {
        const int k = it * 2 + half;
        const int jj = __shfl(j, k);
        const float val = lmain[k * 33 + col];
        unsafeAtomicAdd(&agg[jj * CH + col], val);
    }
    __syncthreads();
    // ---- PASS B: channels 32..66 -> cols 0..31 for mv ch 32..63 ----
#pragma unroll
    for (int c = 32; c < 64; c++) {
        const int qq = (c - 16) / 3, r = (c - 16) - qq * 3;
        row[c - 32] = (r == 0) ? u0[qq] : (r == 1) ? u1[qq] : u2[qq];
    }
    __syncthreads();
#pragma unroll 4
    for (int it = 0; it < 32; it++) {
        const int k = it * 2 + half;
        const int jj = __shfl(j, k);
        const float val = lmain[k * 33 + col];
        unsafeAtomicAdd(&agg[jj * CH + 32 + col], val);
    }
    // ---- a_v flush: 16 edges x 3 comps per iteration (48 lanes) ----
    const int t3 = lane / 3;
    const int c3 = lane - t3 * 3;
#pragma unroll
    for (int it = 0; it < 4; it++) {
        const int kk = (it * 16 + t3) & 63;
        const int jj = __shfl(j, kk);
        if (lane < 48) {
            const float val = lav[kk * 5 + c3];
            unsafeAtomicAdd(&agg[jj * CH + 64 + c3], val);
        }
    }
}

// 256 threads = 4 waves; block handles 64 nodes; wave w owns channel slice c/d in [4w,4w+4) (+16 on w3).
__global__ __launch_bounds__(256, 2) void node_kernel(
    float* __restrict__ s, float4* __restrict__ v4,
    float* __restrict__ agg, const float* __restrict__ cntb,
    const float* __restrict__ nWs, const float* __restrict__ nbs, const float* __restrict__ nWv,
    const float* __restrict__ fWs, const float* __restrict__ fbs, const float* __restrict__ fWv,
    float* __restrict__ out, int zero_agg) {
    __shared__ float nsl[64 * 17];     // per-node ns, stride 17 (conflict-free)
    __shared__ float part[21 * 256];   // partials: [t][w][lane]
    const int tid = threadIdx.x;
    const int lane = tid & 63;
    const int w = tid >> 6;
    const int n0 = blockIdx.x * 64 + lane;
    const bool valid = n0 < N_NODES;
    const int n = valid ? n0 : 0;
    const float inv = 1.0f / 319999.0f;  // 1/(E-1)
    const float cnt = cntb[n];
    const float f = inv / fmaxf(cnt, 1.0f);
    float* ag = agg + n * CH;
    const int c0 = w * 4;
    const bool w3 = (w == 3);

    // own slice of ys / yv
    float yso[4];
#pragma unroll
    for (int k = 0; k < 4; k++) yso[k] = ag[c0 + k] * f;
    const float ys16 = cnt * f;
    float yvo[4][3];
#pragma unroll
    for (int k = 0; k < 4; k++) {
        const int d = c0 + k;
        yvo[k][0] = ag[16 + d * 3 + 0] * f;
        yvo[k][1] = ag[16 + d * 3 + 1] * f;
        yvo[k][2] = ag[16 + d * 3 + 2] * f;
    }
    float yv16[3] = {ag[64] * f, ag[65] * f, ag[66] * f};
    const float4 nvv = v4[n];
    float nv0 = nvv.x, nv1 = nvv.y, nv2 = nvv.z;

    if (w == 0) {
        const float4* srow = (const float4*)(s + n * 16);
        const float4 A = srow[0], B = srow[1], C = srow[2], D = srow[3];
        float* p = nsl + lane * 17;
        p[0] = A.x; p[1] = A.y; p[2] = A.z; p[3] = A.w;
        p[4] = B.x; p[5] = B.y; p[6] = B.z; p[7] = B.w;
        p[8] = C.x; p[9] = C.y; p[10] = C.z; p[11] = C.w;
        p[12] = D.x; p[13] = D.y; p[14] = D.z; p[15] = D.w;
    }
    __syncthreads();

    float nsreg[16];
#pragma unroll 1
    for (int b = 0; b < 2; b++) {
        const float* W = nWs + b * 289 * 17;
        const float* Wv = nWv + b * 289;
        const float* bb = nbs + b * 17;
        float acc[17];
#pragma unroll
        for (int o = 0; o < 17; o++) acc[o] = (w == 0) ? bb[o] : 0.f;
        float gam[4] = {0.f, 0.f, 0.f, 0.f};
        float gam16 = 0.f;
#pragma unroll 2
        for (int a = 0; a < 16; a++) {
            const float xa = nsl[lane * 17 + a];
            const float* Wa = W + (a * 17 + c0) * 17;
#pragma unroll
            for (int k = 0; k < 4; k++) {
                const float cf = xa * yso[k];
#pragma unroll
                for (int o = 0; o < 17; o++) acc[o] += cf * Wa[k * 17 + o];
            }
            const float* Wva = Wv + a * 17 + c0;
#pragma unroll
            for (int k = 0; k < 4; k++) gam[k] += xa * Wva[k];
            if (w3) {
                const float cf = xa * ys16;
                const float* W16 = W + (a * 17 + 16) * 17;
#pragma unroll
                for (int o = 0; o < 17; o++) acc[o] += cf * W16[o];
                gam16 += xa * Wv[a * 17 + 16];
            }
        }
        // vv part (own d slice)
#pragma unroll
        for (int k = 0; k < 4; k++) {
            const int d = c0 + k;
            const float cf = nv0 * yvo[k][0] + nv1 * yvo[k][1] + nv2 * yvo[k][2];
            const float* Wp = W + (272 + d) * 17;
#pragma unroll
            for (int o = 0; o < 17; o++) acc[o] += cf * Wp[o];
        }
        if (w3) {
            const float cf = nv0 * yv16[0] + nv1 * yv16[1] + nv2 * yv16[2];
            const float* Wp = W + (272 + 16) * 17;
#pragma unroll
            for (int o = 0; o < 17; o++) acc[o] += cf * Wp[o];
        }
        // vl & sc2 partials
        float vl0 = 0.f, vl1 = 0.f, vl2 = 0.f, sc2 = 0.f;
#pragma unroll
        for (int k = 0; k < 4; k++) {
            vl0 += gam[k] * yvo[k][0]; vl1 += gam[k] * yvo[k][1]; vl2 += gam[k] * yvo[k][2];
            sc2 += yso[k] * Wv[272 + c0 + k];
        }
        if (w3) {
            vl0 += gam16 * yv16[0]; vl1 += gam16 * yv16[1]; vl2 += gam16 * yv16[2];
            sc2 += ys16 * Wv[272 + 16];
        }
        // write partials [t][w][lane]
#pragma unroll
        for (int o = 0; o < 17; o++) part[o * 256 + tid] = acc[o];
        part[17 * 256 + tid] = vl0;
        part[18 * 256 + tid] = vl1;
        part[19 * 256 + tid] = vl2;
        part[20 * 256 + tid] = sc2;
        __syncthreads();
        float tot[21];
#pragma unroll
        for (int t = 0; t < 21; t++)
            tot[t] = part[t * 256 + lane] + part[t * 256 + 64 + lane] +
                     part[t * 256 + 128 + lane] + part[t * 256 + 192 + lane];
        const float g = sigm(tot[0]);
#pragma unroll
        for (int a = 0; a < 16; a++) nsreg[a] = gelu(tot[1 + a]);
        const float nx = (tot[17] + tot[20] * nv0) * g;
        const float ny = (tot[18] + tot[20] * nv1) * g;
        const float nz = (tot[19] + tot[20] * nv2) * g;
        nv0 = nx; nv1 = ny; nv2 = nz;
        if (b == 0 && w == 0) {
            float* p = nsl + lane * 17;
#pragma unroll
            for (int a = 0; a < 16; a++) p[a] = nsreg[a];
        }
        __syncthreads();
    }
    // final linear + residual (computed redundantly by all waves; only w0 stores)
    float so[16];
#pragma unroll
    for (int a = 0; a < 16; a++) so[a] = fbs[a];
#pragma unroll
    for (int p = 0; p < 16; p++) {
        const float x = nsreg[p];
#pragma unroll
        for (int a = 0; a < 16; a++) so[a] += x * fWs[p * 16 + a];
    }
    if (valid && w == 0) {
        const float fw = fWv[0];
        float sn[16];
#pragma unroll
        for (int a = 0; a < 16; a++) { sn[a] = s[n * 16 + a] + so[a]; }
#pragma unroll
        for (int a = 0; a < 16; a++) s[n * 16 + a] = sn[a];
        const float w0o = nvv.x + nv0 * fw;
        const float w1o = nvv.y + nv1 * fw;
        const float w2o = nvv.z + nv2 * fw;
        v4[n] = make_float4(w0o, w1o, w2o, 0.f);
        if (out) {
#pragma unroll
            for (int a = 0; a < 16; a++) out[n * 19 + a] = sn[a];
            out[n * 19 + 16] = w0o;
            out[n * 19 + 17] = w1o;
            out[n * 19 + 18] = w2o;
        }
        if (zero_agg) {
            float4* agz = (float4*)ag;
#pragma unroll
            for (int k = 0; k < 17; k++) agz[k] = make_float4(0.f, 0.f, 0.f, 0.f);
        }
    }
}

extern "C" void kernel_launch(void* const* d_in, const int* in_sizes, int n_in,
                              void* d_out, int out_size, void* d_ws, size_t ws_size,
                              hipStream_t stream) {
    const float* node_scalars = (const float*)d_in[0];
    const float* node_pos = (const float*)d_in[1];
    const int* senders = (const int*)d_in[2];
    const int* receivers = (const int*)d_in[3];
    const float* eWs0 = (const float*)d_in[4];
    const float* ebs0 = (const float*)d_in[5];
    const float* eWv0 = (const float*)d_in[6];
    const float* eWs1 = (const float*)d_in[7];
    const float* ebs1 = (const float*)d_in[8];
    const float* eWv1 = (const float*)d_in[9];
    const float* nWs = (const float*)d_in[10];
    const float* nbs = (const float*)d_in[11];
    const float* nWv = (const float*)d_in[12];
    const float* fWs = (const float*)d_in[13];
    const float* fbs = (const float*)d_in[14];
    const float* fWv = (const float*)d_in[15];

    float* ws = (float*)d_ws;
    float* s = ws;                        // N*16
    float* v = s + N_NODES * 16;          // N*4 (float4)
    float* agg = v + N_NODES * 4;         // N*CH
    float* cnt = agg + N_NODES * CH;      // N
    float* out = (float*)d_out;
    float4* v4 = (float4*)v;

    init_kernel<<<(N_NODES * 16 + 255) / 256, 256, 0, stream>>>(node_scalars, node_pos, s, v4, cnt);
    count_kernel<<<(N_EDGES + 255) / 256, 256, 0, stream>>>(receivers, cnt);
    hipMemsetAsync(agg, 0, (size_t)N_NODES * CH * sizeof(float), stream);
    for (int t = 0; t < 3; t++) {
        edge_kernel<<<N_EDGES / 64, 64, 0, stream>>>(
            (const float4*)s, (const float4*)v4, senders, receivers,
            eWs0 + t * 34 * 32, ebs0 + t * 32, eWv0 + t * 34 * 16,
            eWs1 + t * 32 * 32, ebs1 + t * 32, eWv1 + t * 32 * 16,
            agg);
        node_kernel<<<(N_NODES + 63) / 64, 256, 0, stream>>>(
            s, v4, agg, cnt,
            nWs + t * 2 * 289 * 17, nbs + t * 2 * 17, nWv + t * 2 * 289,
            fWs + t * 256, fbs + t * 16, fWv + t,
            (t == 2) ? out : nullptr, (t < 2) ? 1 : 0);
    }
}

// Round 4
// 844.094 us; speedup vs baseline: 1.9790x; 1.9790x over previous
//
#include <hip/hip_runtime.h>

#define N_NODES 20000
#define N_EDGES 320000
#define CH 68
#define LDSROW 69  // stride 69: lane-stride 5 mod 32, coprime -> conflict-free staging

__device__ __forceinline__ float sigm(float x) { return 1.0f / (1.0f + __expf(-x)); }
// jax.nn.gelu approximate=True == x*sigmoid(1.5957691*(x+0.044715x^3))
__device__ __forceinline__ float gelu(float x) {
    return x * sigm(1.5957691216057308f * (x + 0.044715f * x * x * x));
}

__global__ void init_kernel(const float* __restrict__ s0, const float* __restrict__ p0,
                            float* __restrict__ s, float4* __restrict__ v4,
                            float* __restrict__ cnt) {
    int idx = blockIdx.x * 256 + threadIdx.x;
    if (idx < N_NODES * 16) s[idx] = s0[idx];
    if (idx < N_NODES) {
        v4[idx] = make_float4(p0[idx * 3], p0[idx * 3 + 1], p0[idx * 3 + 2], 0.f);
        cnt[idx] = 0.f;
    }
}

__global__ void count_kernel(const int* __restrict__ rcv, float* __restrict__ cnt) {
    int e = blockIdx.x * 256 + threadIdx.x;
    if (e < N_EDGES) unsafeAtomicAdd(&cnt[rcv[e]], 1.0f);
}

__global__ __launch_bounds__(64) void edge_kernel(
    const float4* __restrict__ s4, const float4* __restrict__ v4,
    const int* __restrict__ snd, const int* __restrict__ rcv,
    const float* __restrict__ Ws0, const float* __restrict__ bs0, const float* __restrict__ Wv0,
    const float* __restrict__ Ws1, const float* __restrict__ bs1, const float* __restrict__ Wv1,
    float* __restrict__ agg) {
    __shared__ float lds[64 * LDSROW];
    const int lane = threadIdx.x;
    const int e = blockIdx.x * 64 + lane;  // grid = 5000 covers N_EDGES exactly
    const int i = snd[e], j = rcv[e];

    const float4 vi4 = v4[i], vj4 = v4[j];
    const float vi0 = vi4.x, vi1 = vi4.y, vi2 = vi4.z;
    const float vj0 = vj4.x, vj1 = vj4.y, vj2 = vj4.z;
    const float r0 = vi0 - vj0, r1 = vi1 - vj1, r2 = vi2 - vj2;
    const float nrm = sqrtf(r0 * r0 + r1 * r1 + r2 * r2);
    const float scl = 1.7320508075688772f / (nrm + 1e-8f);  // sqrt(3) * rhat
    const float a0 = r0 * scl, a1 = r1 * scl, a2 = r2 * scl;

    float xs[32];
    {
        float4 A = s4[i * 4 + 0], B = s4[i * 4 + 1], C = s4[i * 4 + 2], D = s4[i * 4 + 3];
        xs[0] = A.x; xs[1] = A.y; xs[2] = A.z; xs[3] = A.w;
        xs[4] = B.x; xs[5] = B.y; xs[6] = B.z; xs[7] = B.w;
        xs[8] = C.x; xs[9] = C.y; xs[10] = C.z; xs[11] = C.w;
        xs[12] = D.x; xs[13] = D.y; xs[14] = D.z; xs[15] = D.w;
        A = s4[j * 4 + 0]; B = s4[j * 4 + 1]; C = s4[j * 4 + 2]; D = s4[j * 4 + 3];
        xs[16] = A.x; xs[17] = A.y; xs[18] = A.z; xs[19] = A.w;
        xs[20] = B.x; xs[21] = B.y; xs[22] = B.z; xs[23] = B.w;
        xs[24] = C.x; xs[25] = C.y; xs[26] = C.z; xs[27] = C.w;
        xs[28] = D.x; xs[29] = D.y; xs[30] = D.z; xs[31] = D.w;
    }
    const float di = vi0 * a0 + vi1 * a1 + vi2 * a2;
    const float dj = vj0 * a0 + vj1 * a1 + vj2 * a2;

    // ---- TPLG 0 ----
    float sl[32];
#pragma unroll
    for (int o = 0; o < 32; o++) sl[o] = bs0[o] + di * Ws0[32 * 32 + o] + dj * Ws0[33 * 32 + o];
    float al[16];
#pragma unroll
    for (int q = 0; q < 16; q++) al[q] = 0.f;
#pragma unroll
    for (int p = 0; p < 32; p++) {
        const float x = xs[p];
#pragma unroll
        for (int o = 0; o < 32; o++) sl[o] += x * Ws0[p * 32 + o];
#pragma unroll
        for (int q = 0; q < 16; q++) al[q] += x * Wv0[p * 16 + q];
    }
    float ms[16], mv0[16], mv1[16], mv2[16];
#pragma unroll
    for (int q = 0; q < 16; q++) {
        const float g = sigm(sl[q]);
        const float w32 = Wv0[32 * 16 + q], w33 = Wv0[33 * 16 + q];
        mv0[q] = (al[q] * a0 + w32 * vi0 + w33 * vj0) * g;
        mv1[q] = (al[q] * a1 + w32 * vi1 + w33 * vj1) * g;
        mv2[q] = (al[q] * a2 + w32 * vi2 + w33 * vj2) * g;
    }
#pragma unroll
    for (int p = 0; p < 16; p++) ms[p] = gelu(sl[16 + p]);

    // ---- TPLG 1 ----
    float sl2[32];
#pragma unroll
    for (int o = 0; o < 32; o++) sl2[o] = bs1[o];
#pragma unroll
    for (int p = 0; p < 16; p++) {
        const float x = ms[p];
#pragma unroll
        for (int o = 0; o < 32; o++) sl2[o] += x * Ws1[p * 32 + o];
    }
#pragma unroll
    for (int q = 0; q < 16; q++) {
        const float x = mv0[q] * a0 + mv1[q] * a1 + mv2[q] * a2;
#pragma unroll
        for (int o = 0; o < 32; o++) sl2[o] += x * Ws1[(16 + q) * 32 + o];
    }

    // stage full row: [0..15]=scalars, [16..63]=mv interleaved q*3+r, [64..66]=a_v
    float* row = &lds[lane * LDSROW];
#pragma unroll
    for (int q = 0; q < 16; q++) {
        const float g = sigm(sl2[q]);
        float be = 0.f;
#pragma unroll
        for (int p = 0; p < 16; p++) be += ms[p] * Wv1[p * 16 + q];
        float u0 = be * a0, u1 = be * a1, u2 = be * a2;
#pragma unroll
        for (int p = 0; p < 16; p++) {
            const float w = Wv1[(16 + p) * 16 + q];
            u0 += mv0[p] * w; u1 += mv1[p] * w; u2 += mv2[p] * w;
        }
        row[16 + q * 3 + 0] = u0 * g;
        row[16 + q * 3 + 1] = u1 * g;
        row[16 + q * 3 + 2] = u2 * g;
    }
#pragma unroll
    for (int p = 0; p < 16; p++) row[p] = gelu(sl2[16 + p]);
    row[64] = a0; row[65] = a1; row[66] = a2;
    __syncthreads();

    // wave-coalesced atomic flush: ONE node per iteration, full row in one burst
    // (temporal locality of the whole row is what keeps L2 lines resident —
    //  splitting this into passes tripled HBM traffic in round 3)
#pragma unroll 4
    for (int k = 0; k < 64; k++) {
        const int jj = __shfl(j, k);
        const float val = lds[k * LDSROW + lane];
        unsafeAtomicAdd(&agg[jj * CH + lane], val);
        if (lane < 3) {
            const float v2 = lds[k * LDSROW + 64 + lane];
            unsafeAtomicAdd(&agg[jj * CH + 64 + lane], v2);
        }
    }
}

// 256 threads = 4 waves; block handles 64 nodes; wave w owns channel slice c/d in [4w,4w+4) (+16 on w3).
__global__ __launch_bounds__(256, 2) void node_kernel(
    float* __restrict__ s, float4* __restrict__ v4,
    float* __restrict__ agg, const float* __restrict__ cntb,
    const float* __restrict__ nWs, const float* __restrict__ nbs, const float* __restrict__ nWv,
    const float* __restrict__ fWs, const float* __restrict__ fbs, const float* __restrict__ fWv,
    float* __restrict__ out, int zero_agg) {
    __shared__ float nsl[64 * 17];     // per-node ns, stride 17 (conflict-free)
    __shared__ float part[21 * 256];   // partials: [t][w][lane]
    const int tid = threadIdx.x;
    const int lane = tid & 63;
    const int w = tid >> 6;
    const int n0 = blockIdx.x * 64 + lane;
    const bool valid = n0 < N_NODES;
    const int n = valid ? n0 : 0;
    const float inv = 1.0f / 319999.0f;  // 1/(E-1)
    const float cnt = cntb[n];
    const float f = inv / fmaxf(cnt, 1.0f);
    float* ag = agg + n * CH;
    const int c0 = w * 4;
    const bool w3 = (w == 3);

    float yso[4];
#pragma unroll
    for (int k = 0; k < 4; k++) yso[k] = ag[c0 + k] * f;
    const float ys16 = cnt * f;
    float yvo[4][3];
#pragma unroll
    for (int k = 0; k < 4; k++) {
        const int d = c0 + k;
        yvo[k][0] = ag[16 + d * 3 + 0] * f;
        yvo[k][1] = ag[16 + d * 3 + 1] * f;
        yvo[k][2] = ag[16 + d * 3 + 2] * f;
    }
    float yv16[3] = {ag[64] * f, ag[65] * f, ag[66] * f};
    const float4 nvv = v4[n];
    float nv0 = nvv.x, nv1 = nvv.y, nv2 = nvv.z;

    if (w == 0) {
        const float4* srow = (const float4*)(s + n * 16);
        const float4 A = srow[0], B = srow[1], C = srow[2], D = srow[3];
        float* p = nsl + lane * 17;
        p[0] = A.x; p[1] = A.y; p[2] = A.z; p[3] = A.w;
        p[4] = B.x; p[5] = B.y; p[6] = B.z; p[7] = B.w;
        p[8] = C.x; p[9] = C.y; p[10] = C.z; p[11] = C.w;
        p[12] = D.x; p[13] = D.y; p[14] = D.z; p[15] = D.w;
    }
    __syncthreads();

    float nsreg[16];
#pragma unroll 1
    for (int b = 0; b < 2; b++) {
        const float* W = nWs + b * 289 * 17;
        const float* Wv = nWv + b * 289;
        const float* bb = nbs + b * 17;
        float acc[17];
#pragma unroll
        for (int o = 0; o < 17; o++) acc[o] = (w == 0) ? bb[o] : 0.f;
        float gam[4] = {0.f, 0.f, 0.f, 0.f};
        float gam16 = 0.f;
#pragma unroll 2
        for (int a = 0; a < 16; a++) {
            const float xa = nsl[lane * 17 + a];
            const float* Wa = W + (a * 17 + c0) * 17;
#pragma unroll
            for (int k = 0; k < 4; k++) {
                const float cf = xa * yso[k];
#pragma unroll
                for (int o = 0; o < 17; o++) acc[o] += cf * Wa[k * 17 + o];
            }
            const float* Wva = Wv + a * 17 + c0;
#pragma unroll
            for (int k = 0; k < 4; k++) gam[k] += xa * Wva[k];
            if (w3) {
                const float cf = xa * ys16;
                const float* W16 = W + (a * 17 + 16) * 17;
#pragma unroll
                for (int o = 0; o < 17; o++) acc[o] += cf * W16[o];
                gam16 += xa * Wv[a * 17 + 16];
            }
        }
#pragma unroll
        for (int k = 0; k < 4; k++) {
            const int d = c0 + k;
            const float cf = nv0 * yvo[k][0] + nv1 * yvo[k][1] + nv2 * yvo[k][2];
            const float* Wp = W + (272 + d) * 17;
#pragma unroll
            for (int o = 0; o < 17; o++) acc[o] += cf * Wp[o];
        }
        if (w3) {
            const float cf = nv0 * yv16[0] + nv1 * yv16[1] + nv2 * yv16[2];
            const float* Wp = W + (272 + 16) * 17;
#pragma unroll
            for (int o = 0; o < 17; o++) acc[o] += cf * Wp[o];
        }
        float vl0 = 0.f, vl1 = 0.f, vl2 = 0.f, sc2 = 0.f;
#pragma unroll
        for (int k = 0; k < 4; k++) {
            vl0 += gam[k] * yvo[k][0]; vl1 += gam[k] * yvo[k][1]; vl2 += gam[k] * yvo[k][2];
            sc2 += yso[k] * Wv[272 + c0 + k];
        }
        if (w3) {
            vl0 += gam16 * yv16[0]; vl1 += gam16 * yv16[1]; vl2 += gam16 * yv16[2];
            sc2 += ys16 * Wv[272 + 16];
        }
#pragma unroll
        for (int o = 0; o < 17; o++) part[o * 256 + tid] = acc[o];
        part[17 * 256 + tid] = vl0;
        part[18 * 256 + tid] = vl1;
        part[19 * 256 + tid] = vl2;
        part[20 * 256 + tid] = sc2;
        __syncthreads();
        float tot[21];
#pragma unroll
        for (int t = 0; t < 21; t++)
            tot[t] = part[t * 256 + lane] + part[t * 256 + 64 + lane] +
                     part[t * 256 + 128 + lane] + part[t * 256 + 192 + lane];
        const float g = sigm(tot[0]);
#pragma unroll
        for (int a = 0; a < 16; a++) nsreg[a] = gelu(tot[1 + a]);
        const float nx = (tot[17] + tot[20] * nv0) * g;
        const float ny = (tot[18] + tot[20] * nv1) * g;
        const float nz = (tot[19] + tot[20] * nv2) * g;
        nv0 = nx; nv1 = ny; nv2 = nz;
        if (b == 0 && w == 0) {
            float* p = nsl + lane * 17;
#pragma unroll
            for (int a = 0; a < 16; a++) p[a] = nsreg[a];
        }
        __syncthreads();
    }
    float so[16];
#pragma unroll
    for (int a = 0; a < 16; a++) so[a] = fbs[a];
#pragma unroll
    for (int p = 0; p < 16; p++) {
        const float x = nsreg[p];
#pragma unroll
        for (int a = 0; a < 16; a++) so[a] += x * fWs[p * 16 + a];
    }
    if (valid && w == 0) {
        const float fw = fWv[0];
        float sn[16];
#pragma unroll
        for (int a = 0; a < 16; a++) { sn[a] = s[n * 16 + a] + so[a]; }
#pragma unroll
        for (int a = 0; a < 16; a++) s[n * 16 + a] = sn[a];
        const float w0o = nvv.x + nv0 * fw;
        const float w1o = nvv.y + nv1 * fw;
        const float w2o = nvv.z + nv2 * fw;
        v4[n] = make_float4(w0o, w1o, w2o, 0.f);
        if (out) {
#pragma unroll
            for (int a = 0; a < 16; a++) out[n * 19 + a] = sn[a];
            out[n * 19 + 16] = w0o;
            out[n * 19 + 17] = w1o;
            out[n * 19 + 18] = w2o;
        }
        if (zero_agg) {
            float4* agz = (float4*)ag;
#pragma unroll
            for (int k = 0; k < 17; k++) agz[k] = make_float4(0.f, 0.f, 0.f, 0.f);
        }
    }
}

extern "C" void kernel_launch(void* const* d_in, const int* in_sizes, int n_in,
                              void* d_out, int out_size, void* d_ws, size_t ws_size,
                              hipStream_t stream) {
    const float* node_scalars = (const float*)d_in[0];
    const float* node_pos = (const float*)d_in[1];
    const int* senders = (const int*)d_in[2];
    const int* receivers = (const int*)d_in[3];
    const float* eWs0 = (const float*)d_in[4];
    const float* ebs0 = (const float*)d_in[5];
    const float* eWv0 = (const float*)d_in[6];
    const float* eWs1 = (const float*)d_in[7];
    const float* ebs1 = (const float*)d_in[8];
    const float* eWv1 = (const float*)d_in[9];
    const float* nWs = (const float*)d_in[10];
    const float* nbs = (const float*)d_in[11];
    const float* nWv = (const float*)d_in[12];
    const float* fWs = (const float*)d_in[13];
    const float* fbs = (const float*)d_in[14];
    const float* fWv = (const float*)d_in[15];

    float* ws = (float*)d_ws;
    float* s = ws;                        // N*16
    float* v = s + N_NODES * 16;          // N*4 (float4)
    float* agg = v + N_NODES * 4;         // N*CH
    float* cnt = agg + N_NODES * CH;      // N
    float* out = (float*)d_out;
    float4* v4 = (float4*)v;

    init_kernel<<<(N_NODES * 16 + 255) / 256, 256, 0, stream>>>(node_scalars, node_pos, s, v4, cnt);
    count_kernel<<<(N_EDGES + 255) / 256, 256, 0, stream>>>(receivers, cnt);
    hipMemsetAsync(agg, 0, (size_t)N_NODES * CH * sizeof(float), stream);
    for (int t = 0; t < 3; t++) {
        edge_kernel<<<N_EDGES / 64, 64, 0, stream>>>(
            (const float4*)s, (const float4*)v4, senders, receivers,
            eWs0 + t * 34 * 32, ebs0 + t * 32, eWv0 + t * 34 * 16,
            eWs1 + t * 32 * 32, ebs1 + t * 32, eWv1 + t * 32 * 16,
            agg);
        node_kernel<<<(N_NODES + 63) / 64, 256, 0, stream>>>(
            s, v4, agg, cnt,
            nWs + t * 2 * 289 * 17, nbs + t * 2 * 17, nWv + t * 2 * 289,
            fWs + t * 256, fbs + t * 16, fWv + t,
            (t == 2) ? out : nullptr, (t < 2) ? 1 : 0);
    }
}